// Round 3
// baseline (51.257 us; speedup 1.0000x reference)
//
#include <hip/hip_runtime.h>

#define B_    16
#define L_    512
#define N_    64
#define D_    256
#define T_    16                 // outputs per thread (t-tile height)
#define NT    (L_ / T_)          // 32 tiles per (b)
#define KROWS (L_ + T_)          // 528 rows: tau = row-16, rows 0..15 are zeros
#define GUARD 4                  // guard rows below Kpad for prefetch underrun

// Kernel A: Kpad[row][d] = sum_n Re( G[n,d] * a[n]^tau ),  tau = row-16
__global__ __launch_bounds__(256)
void build_K(const float* __restrict__ Lre_p, const float* __restrict__ Lim_p,
             const float* __restrict__ Bre_p, const float* __restrict__ Bim_p,
             const float* __restrict__ Pre_p, const float* __restrict__ Pim_p,
             const float* __restrict__ logdt_p,
             float* __restrict__ Kpad)   // points at row 0 (after guard)
{
    __shared__ float U[N_], V[N_];
    const int row = blockIdx.x;          // 0..KROWS-1
    const int tau = row - T_;
    const int d   = threadIdx.x;         // 0..255

    if (tau < 0) {                        // uniform branch per block
        Kpad[row * D_ + d] = 0.f;
        return;
    }

    const float dt = expf(logdt_p[0]);
    if (d < N_) {
        const float Lre = Lre_p[d], Lim = Lim_p[d];
        const float eL  = expf(Lre);
        const float wre = -eL * cosf(Lim);
        const float wim = -eL * sinf(Lim);
        const float ft  = (float)tau;
        const float er  = expf(ft * dt * wre);      // |a|^tau
        float sn, cs;
        sincosf(ft * dt * wim, &sn, &cs);
        const float Ar = er * cs, Ai = er * sn;     // a^tau
        const float Bdre = dt * Bre_p[d], Bdim = dt * Bim_p[d];
        U[d] = Bdre * Ar - Bdim * Ai;
        V[d] = Bdim * Ar + Bdre * Ai;
    }
    __syncthreads();

    float acc = 0.f;
    #pragma unroll 8
    for (int n = 0; n < N_; ++n)
        acc = fmaf(Pre_p[n * D_ + d], U[n],
              fmaf(-Pim_p[n * D_ + d], V[n], acc));
    Kpad[row * D_ + d] = acc;
}

// Kernel B: causal FIR with rolling 16-reg K window + 4-deep prefetch rings.
__global__ __launch_bounds__(256)
void conv_fir(const float* __restrict__ u, const float* __restrict__ Kpad,
              float* __restrict__ y)      // Kpad points at row 0 (after guard)
{
    const int bid = blockIdx.x;              // 0..B_*NT-1
    const int k   = (NT - 1) - (bid >> 4);   // heavy tiles dispatched first
    const int b   = bid & (B_ - 1);
    const int d   = threadIdx.x;

    const float* ub = u + ((size_t)b * L_) * D_ + d;          // + s*D_
    const float* Kb = Kpad + d;                               // + row*D_
    float*       yb = y + ((size_t)b * L_ + k * T_) * D_ + d; // + j*D_

    const int send = T_ * (k + 1);           // history length (multiple of 16)
    const int r0   = T_ * k + T_;            // Kpad row entering at s=0

    float W[16];
    #pragma unroll
    for (int j = 1; j < 16; ++j) W[j] = Kb[(r0 + j) * D_];
    float kr[4], ur[4];
    #pragma unroll
    for (int p = 0; p < 4; ++p) {
        kr[p] = Kb[(r0 - p) * D_];           // rows for s = 0..3
        ur[p] = ub[p * D_];                  // u_s for s = 0..3
    }
    float acc[16];
    #pragma unroll
    for (int j = 0; j < 16; ++j) acc[j] = 0.f;

    for (int s0 = 0; s0 < send; s0 += 16) {
        #pragma unroll
        for (int m = 0; m < 16; ++m) {       // s = s0+m; (j-s)&15 == (j-m)&15
            const float uv = ur[m & 3];
            const float kv = kr[m & 3];
            acc[0] = fmaf(kv, uv, acc[0]);   // j=0: freshly entered K row
            #pragma unroll
            for (int j = 1; j < 16; ++j)
                acc[j] = fmaf(W[(j - m) & 15], uv, acc[j]);
            W[(16 - m) & 15] = kv;           // commit ((-m)&15)
            const int s = s0 + m;            // prefetch s+4 (uniform addrs)
            kr[m & 3] = Kb[(r0 - s - 4) * D_];        // may hit GUARD rows
            const int spf = (s + 4 < L_) ? (s + 4) : (L_ - 1);
            ur[m & 3] = ub[spf * D_];
        }
    }

    #pragma unroll
    for (int j = 0; j < 16; ++j)
        yb[j * D_] = acc[j];
}

extern "C" void kernel_launch(void* const* d_in, const int* in_sizes, int n_in,
                              void* d_out, int out_size, void* d_ws, size_t ws_size,
                              hipStream_t stream) {
    const float* u     = (const float*)d_in[0];
    const float* Lre   = (const float*)d_in[1];
    const float* Lim   = (const float*)d_in[2];
    const float* Bre   = (const float*)d_in[3];
    const float* Bim   = (const float*)d_in[4];
    const float* Pre   = (const float*)d_in[5];
    const float* Pim   = (const float*)d_in[6];
    const float* logdt = (const float*)d_in[7];
    float* y = (float*)d_out;

    float* Kpad0 = (float*)d_ws;             // guard rows live here
    float* Kpad  = Kpad0 + GUARD * D_;       // row 0 of the real table

    build_K<<<KROWS, 256, 0, stream>>>(Lre, Lim, Bre, Bim, Pre, Pim, logdt, Kpad);
    conv_fir<<<B_ * NT, 256, 0, stream>>>(u, Kpad, y);
}